// Round 3
// baseline (224.947 us; speedup 1.0000x reference)
//
#include <hip/hip_runtime.h>

#define N_NODES 50000
#define N_EDGES 800000
#define IN_CH 256
#define HID_CH 128
#define OUT_CH 64
#define CAP 64       // bucket slots/node; deg~Poisson(16), P(deg>=64) ~ 1e-18
#define LBSTRIDE 72  // padded LDS bucket row stride in u16 (144B: 2-way banks max)
#define NBINS 196    // ceil(N/256): bin = dst >> 8
#define PCHUNK 3200
#define PBLOCKS 250  // 250*3200 == N_EDGES
#define SWZ_ELEMS (IN_CH * HID_CH + HID_CH * OUT_CH)  // 40960
#define SWZ_BLOCKS (SWZ_ELEMS / 256)                  // 160
#define NT1 (HID_CH / 16)  // 8 channel tiles, layer 1 (tile = 1.6 MB, pair = 3.2 MB < L2)
#define NT2 (OUT_CH / 16)  // 4 channel tiles, layer 2

typedef _Float16 f16;
typedef _Float16 f16x8 __attribute__((ext_vector_type(8)));
typedef float f32x4 __attribute__((ext_vector_type(4)));
typedef unsigned short u16;
typedef unsigned int u32;

// ---------------- W -> MFMA B-fragment swizzle ----------------
template <int K, int N>
__device__ __forceinline__ void swz(const float* __restrict__ W, f16* __restrict__ Bsw,
                                    int idx) {
    constexpr int NTILES = N / 16;
    int j = idx & 7;
    int lane = (idx >> 3) & 63;
    int rest = idx >> 9;
    int nt = rest % NTILES;
    int ks = rest / NTILES;
    int k = ks * 32 + (lane >> 4) * 8 + j;
    int n = nt * 16 + (lane & 15);
    Bsw[idx] = (f16)W[(size_t)k * N + n];
}

// ---------------- local exclusive scan of binCnt ----------------
__device__ __forceinline__ void scan_local(const int* __restrict__ binCnt,
                                           int* sc, int* vv) {
    const int t = threadIdx.x;
    int v = (t < NBINS) ? binCnt[t] : 0;
    sc[t] = v; vv[t] = v;
    __syncthreads();
    for (int ofs = 1; ofs < 256; ofs <<= 1) {
        int add = (t >= ofs) ? sc[t - ofs] : 0;
        __syncthreads();
        sc[t] += add;
        __syncthreads();
    }
    // sc inclusive; exclusive = sc[t] - vv[t]
}

// ---------------- fused: dst-bin histogram + weight swizzle ----------------
__global__ __launch_bounds__(256) void k_pre(const int* __restrict__ dst,
                                             int* __restrict__ binCnt,
                                             const float* __restrict__ W1,
                                             const float* __restrict__ W2,
                                             f16* __restrict__ B1,
                                             f16* __restrict__ B2) {
    if ((int)blockIdx.x < PBLOCKS) {
        __shared__ int lcnt[NBINS];
        for (int i = threadIdx.x; i < NBINS; i += 256) lcnt[i] = 0;
        __syncthreads();
        int base = blockIdx.x * PCHUNK;
        for (int i = base + (int)threadIdx.x; i < base + PCHUNK; i += 256)
            atomicAdd(&lcnt[dst[i] >> 8], 1);
        __syncthreads();
        for (int i = threadIdx.x; i < NBINS; i += 256)
            if (lcnt[i]) atomicAdd(&binCnt[i], lcnt[i]);
        return;
    }
    int idx = ((int)blockIdx.x - PBLOCKS) * 256 + threadIdx.x;
    if (idx < IN_CH * HID_CH) {
        swz<IN_CH, HID_CH>(W1, B1, idx);
    } else {
        idx -= IN_CH * HID_CH;
        if (idx < HID_CH * OUT_CH) swz<HID_CH, OUT_CH>(W2, B2, idx);
    }
}

// ---------------- place packed (dst<<16|src) codes into bin segments ----------------
__global__ __launch_bounds__(256) void k_place(const int* __restrict__ src,
                                               const int* __restrict__ dst,
                                               const int* __restrict__ binCnt,
                                               int* __restrict__ binCursor,
                                               u32* __restrict__ ebuf, int E) {
    __shared__ u32 codes[PCHUNK];
    __shared__ int sc[256], vv[256];
    __shared__ int lcnt[NBINS], lbase[NBINS], lcur[NBINS];
    scan_local(binCnt, sc, vv);
    for (int i = threadIdx.x; i < NBINS; i += 256) lcnt[i] = 0;
    __syncthreads();
    int base = blockIdx.x * PCHUNK;
    int m = min(PCHUNK, E - base);
    for (int j = threadIdx.x; j < m; j += 256) {
        u32 d = (u32)dst[base + j];
        codes[j] = (d << 16) | (u32)src[base + j];
        atomicAdd(&lcnt[d >> 8], 1);
    }
    __syncthreads();
    for (int i = threadIdx.x; i < NBINS; i += 256) {
        lbase[i] = (sc[i] - vv[i]) + atomicAdd(&binCursor[i], lcnt[i]);
        lcur[i] = 0;
    }
    __syncthreads();
    for (int j = threadIdx.x; j < m; j += 256) {
        u32 c = codes[j];
        int b = c >> 24;
        int p = atomicAdd(&lcur[b], 1);
        ebuf[lbase[b] + p] = c;
    }
}

// ---------------- per-bin CSR build in LDS + cnt + dis ----------------
__global__ __launch_bounds__(256) void k_build(const u32* __restrict__ ebuf,
                                               const int* __restrict__ binCnt,
                                               int* __restrict__ cnt,
                                               float* __restrict__ dis,
                                               u16* __restrict__ bucket, int N) {
    __shared__ int sc[256], vv[256];
    __shared__ int lcnt[256];
    __shared__ u16 lbuck[256 * CAP];   // 32 KB
    scan_local(binCnt, sc, vv);
    int t = threadIdx.x;
    lcnt[t] = 0;
    __syncthreads();
    int b = blockIdx.x;
    int s = sc[b] - vv[b];
    int e = sc[b];
    for (int i = s + t; i < e; i += 256) {
        u32 c = ebuf[i];
        int local = (c >> 16) & 255;
        int p = atomicAdd(&lcnt[local], 1);
        if (p < CAP) lbuck[local * CAP + p] = (u16)(c & 0xFFFFu);
    }
    __syncthreads();
    int nodeBase = b << 8;
    if (nodeBase + t < N) {
        cnt[nodeBase + t] = lcnt[t];
        dis[nodeBase + t] = rsqrtf((float)lcnt[t] + 1.0f);
    }
    // write only the 16B chunks that hold live entries
    const uint4* lsrc = (const uint4*)lbuck;
    uint4* gdst = (uint4*)(bucket + (size_t)nodeBase * CAP);
    for (int idx = t; idx < 256 * CAP / 8; idx += 256) {
        int row = idx >> 3;
        int chunk = idx & 7;
        if (nodeBase + row < N && (chunk << 3) < lcnt[row]) gdst[idx] = lsrc[idx];
    }
}

// ---------------- MFMA fp16 GEMM layer1: g1t = dis[m]*(x @ W1), channel-tiled out ----
__global__ __launch_bounds__(256) void k_gemm1(const float* __restrict__ A,
                                               const f16* __restrict__ Bsw,
                                               const float* __restrict__ dis,
                                               f16* __restrict__ C, int M) {
    constexpr int K = IN_CH, N = HID_CH;
    constexpr int KSTEPS = K / 32, NTILES = N / 16;
    const int tid = threadIdx.x;
    const int wave = tid >> 6, lane = tid & 63;
    const int quad = lane >> 4, l16 = lane & 15;
    int row = blockIdx.x * 64 + wave * 16 + l16;
    const int rowc = row < M ? row : M - 1;

    f32x4 acc[NTILES];
#pragma unroll
    for (int t = 0; t < NTILES; ++t) acc[t] = (f32x4){0.f, 0.f, 0.f, 0.f};

#pragma unroll
    for (int ks = 0; ks < KSTEPS; ++ks) {
        f16x8 afrag;
        const float4* p = (const float4*)(A + (size_t)rowc * K + ks * 32 + quad * 8);
        float4 v0 = p[0], v1 = p[1];
        afrag[0] = (f16)v0.x; afrag[1] = (f16)v0.y;
        afrag[2] = (f16)v0.z; afrag[3] = (f16)v0.w;
        afrag[4] = (f16)v1.x; afrag[5] = (f16)v1.y;
        afrag[6] = (f16)v1.z; afrag[7] = (f16)v1.w;
#pragma unroll
        for (int t = 0; t < NTILES; ++t) {
            f16x8 bfrag = *(const f16x8*)(Bsw + (((size_t)ks * NTILES + t) * 64 + lane) * 8);
            acc[t] = __builtin_amdgcn_mfma_f32_16x16x32_f16(afrag, bfrag, acc[t], 0, 0, 0);
        }
    }

    int rbase = blockIdx.x * 64 + wave * 16 + quad * 4;
#pragma unroll
    for (int r = 0; r < 4; ++r) {
        int gr = rbase + r;
        if (gr < M) {
            float d = dis[gr];
#pragma unroll
            for (int t = 0; t < NTILES; ++t)   // tiled: [t][node][16]
                C[((size_t)t * N_NODES + gr) * 16 + l16] = (f16)(acc[t][r] * d);
        }
    }
}

// ---------------- fused pull1 + gemm2, L2-resident tile-pair gathers ----------------
// g1t layout [NT1][N][16]. Phase A: per tile-pair (3.2MB, L2-fit) gather
// agg[u,nt*16+c] = relu(du*(g1t[nt][u]+sum_s g1t[nt][s]) + b1) -> LDS.
// Bucket rows staged once in LDS, reused across all 4 pairs.
// Phase B: g2t[nt][u][16] = dis[u] * (agg[u,:] @ W2), MFMA from LDS.
__global__ __launch_bounds__(256) void k_pullgemm(const f16* __restrict__ g1t,
                                                  const float* __restrict__ dis,
                                                  const float* __restrict__ b1,
                                                  const int* __restrict__ cnt,
                                                  const u16* __restrict__ bucket,
                                                  const f16* __restrict__ B2sw,
                                                  f16* __restrict__ g2t) {
    constexpr int LDSW = HID_CH + 8;       // 136 f16 = 272 B row stride
    __shared__ f16 aggl[64 * LDSW];        // 17.4 KB
    __shared__ u16 lbuck[64 * LBSTRIDE];   // 9.2 KB
    __shared__ int lcnt[64];
    __shared__ float ldis[64];
    const int tid = threadIdx.x;
    const int blockBase = (int)blockIdx.x * 64;
    const int gmax = N_NODES - blockBase;  // live rows in this block

    // stage bucket rows (coalesced 16B), cnt, dis
    {
        const uint4* bsrc = (const uint4*)(bucket + (size_t)blockBase * CAP);
        for (int i = tid; i < 64 * (CAP / 8); i += 256) {
            int r = i >> 3, c = i & 7;
            uint4 v = make_uint4(0, 0, 0, 0);
            if (r < gmax) v = bsrc[(r << 3) + c];
            *(uint4*)(lbuck + r * LBSTRIDE + (c << 3)) = v;
        }
        if (tid < 64) {
            int u = blockBase + tid;
            int n = (u < N_NODES) ? cnt[u] : 0;
            lcnt[tid] = n > CAP ? CAP : n;
            ldis[tid] = (u < N_NODES) ? dis[u] : 0.f;
        }
    }
    __syncthreads();

    // ---- phase A: 4 tile-pair iterations ----
    const int sub = tid & 1;        // 8-ch half within 16-ch tile
    const int sl = (tid >> 1) & 1;  // tile within pair
    const int nl = tid >> 2;        // node slot 0..63
    const int u = blockBase + nl;
    const int n = lcnt[nl];
    const float du = ldis[nl];
    const u16* lrow = lbuck + nl * LBSTRIDE;

    for (int it = 0; it < NT1 / 2; ++it) {
        int nt = it * 2 + sl;
        f16x8 o;
        if (u < N_NODES) {
            const f16* gp = g1t + (size_t)nt * N_NODES * 16 + sub * 8;
            f16x8 sv = *(const f16x8*)(gp + (size_t)u * 16);
            float a[8];
#pragma unroll
            for (int j = 0; j < 8; ++j) a[j] = (float)sv[j];

            int k = 0;
            for (; k + 8 <= n; k += 8) {
                uint4 iv = *(const uint4*)(lrow + k);
                int s0 = iv.x & 0xFFFF, s1 = iv.x >> 16;
                int s2 = iv.y & 0xFFFF, s3 = iv.y >> 16;
                int s4 = iv.z & 0xFFFF, s5 = iv.z >> 16;
                int s6 = iv.w & 0xFFFF, s7 = iv.w >> 16;
                f16x8 v0 = *(const f16x8*)(gp + (size_t)s0 * 16);
                f16x8 v1 = *(const f16x8*)(gp + (size_t)s1 * 16);
                f16x8 v2 = *(const f16x8*)(gp + (size_t)s2 * 16);
                f16x8 v3 = *(const f16x8*)(gp + (size_t)s3 * 16);
                f16x8 v4 = *(const f16x8*)(gp + (size_t)s4 * 16);
                f16x8 v5 = *(const f16x8*)(gp + (size_t)s5 * 16);
                f16x8 v6 = *(const f16x8*)(gp + (size_t)s6 * 16);
                f16x8 v7 = *(const f16x8*)(gp + (size_t)s7 * 16);
#pragma unroll
                for (int j = 0; j < 8; ++j)
                    a[j] += (((float)v0[j] + (float)v1[j]) + ((float)v2[j] + (float)v3[j])) +
                            (((float)v4[j] + (float)v5[j]) + ((float)v6[j] + (float)v7[j]));
            }
            if (k + 4 <= n) {
                ushort4 s4v = *(const ushort4*)(lrow + k);
                f16x8 v0 = *(const f16x8*)(gp + (size_t)s4v.x * 16);
                f16x8 v1 = *(const f16x8*)(gp + (size_t)s4v.y * 16);
                f16x8 v2 = *(const f16x8*)(gp + (size_t)s4v.z * 16);
                f16x8 v3 = *(const f16x8*)(gp + (size_t)s4v.w * 16);
#pragma unroll
                for (int j = 0; j < 8; ++j)
                    a[j] += ((float)v0[j] + (float)v1[j]) + ((float)v2[j] + (float)v3[j]);
                k += 4;
            }
            for (; k < n; ++k) {
                f16x8 v = *(const f16x8*)(gp + (size_t)lrow[k] * 16);
#pragma unroll
                for (int j = 0; j < 8; ++j) a[j] += (float)v[j];
            }

            const float4* bp = (const float4*)(b1 + nt * 16 + sub * 8);
            float4 B0 = bp[0], B1v = bp[1];
            float bv[8] = {B0.x, B0.y, B0.z, B0.w, B1v.x, B1v.y, B1v.z, B1v.w};
#pragma unroll
            for (int j = 0; j < 8; ++j) {
                float t = fmaf(du, a[j], bv[j]);
                o[j] = (f16)(t > 0.f ? t : 0.f);
            }
        } else {
#pragma unroll
            for (int j = 0; j < 8; ++j) o[j] = (f16)0;
        }
        *(f16x8*)(aggl + (size_t)nl * LDSW + nt * 16 + sub * 8) = o;
    }
    __syncthreads();

    // ---- phase B: 64x64 MFMA tile, K=128, A from LDS ----
    constexpr int KSTEPS = HID_CH / 32, NTILES = OUT_CH / 16;
    const int wave = tid >> 6, lane = tid & 63;
    const int quad = lane >> 4, l16 = lane & 15;
    const int lrowA = wave * 16 + l16;

    f32x4 acc[NTILES];
#pragma unroll
    for (int t = 0; t < NTILES; ++t) acc[t] = (f32x4){0.f, 0.f, 0.f, 0.f};

#pragma unroll
    for (int ks = 0; ks < KSTEPS; ++ks) {
        f16x8 afrag = *(const f16x8*)(aggl + (size_t)lrowA * LDSW + ks * 32 + quad * 8);
#pragma unroll
        for (int t = 0; t < NTILES; ++t) {
            f16x8 bfrag = *(const f16x8*)(B2sw + (((size_t)ks * NTILES + t) * 64 + lane) * 8);
            acc[t] = __builtin_amdgcn_mfma_f32_16x16x32_f16(afrag, bfrag, acc[t], 0, 0, 0);
        }
    }

    int rbase = blockBase + wave * 16 + quad * 4;
#pragma unroll
    for (int r = 0; r < 4; ++r) {
        int gr = rbase + r;
        if (gr < N_NODES) {
            float d = dis[gr];
#pragma unroll
            for (int t = 0; t < NTILES; ++t)   // tiled: [t][node][16]
                g2t[((size_t)t * N_NODES + gr) * 16 + l16] = (f16)(acc[t][r] * d);
        }
    }
}

// ---------------- pull2: L2-resident tile-pair gathers over g2t ----------------
// out[u, nt*16+c] = relu( du*(g2t[nt][u]+sum g2t[nt][s]) + b2 ), fp32 row-major.
__global__ __launch_bounds__(256) void k_pull2(const f16* __restrict__ g2t,
                                               const float* __restrict__ dis,
                                               const float* __restrict__ b2,
                                               const int* __restrict__ cnt,
                                               const u16* __restrict__ bucket,
                                               float* __restrict__ out) {
    __shared__ u16 lbuck[64 * LBSTRIDE];   // 9.2 KB
    __shared__ int lcnt[64];
    __shared__ float ldis[64];
    const int tid = threadIdx.x;
    const int blockBase = (int)blockIdx.x * 64;
    const int gmax = N_NODES - blockBase;

    {
        const uint4* bsrc = (const uint4*)(bucket + (size_t)blockBase * CAP);
        for (int i = tid; i < 64 * (CAP / 8); i += 256) {
            int r = i >> 3, c = i & 7;
            uint4 v = make_uint4(0, 0, 0, 0);
            if (r < gmax) v = bsrc[(r << 3) + c];
            *(uint4*)(lbuck + r * LBSTRIDE + (c << 3)) = v;
        }
        if (tid < 64) {
            int u = blockBase + tid;
            int n = (u < N_NODES) ? cnt[u] : 0;
            lcnt[tid] = n > CAP ? CAP : n;
            ldis[tid] = (u < N_NODES) ? dis[u] : 0.f;
        }
    }
    __syncthreads();

    const int sub = tid & 1;
    const int sl = (tid >> 1) & 1;
    const int nl = tid >> 2;
    const int u = blockBase + nl;
    if (u >= N_NODES) return;
    const int n = lcnt[nl];
    const float du = ldis[nl];
    const u16* lrow = lbuck + nl * LBSTRIDE;

    for (int it = 0; it < NT2 / 2; ++it) {
        int nt = it * 2 + sl;
        const f16* gp = g2t + (size_t)nt * N_NODES * 16 + sub * 8;
        f16x8 sv = *(const f16x8*)(gp + (size_t)u * 16);
        float a[8];
#pragma unroll
        for (int j = 0; j < 8; ++j) a[j] = (float)sv[j];

        int k = 0;
        for (; k + 8 <= n; k += 8) {
            uint4 iv = *(const uint4*)(lrow + k);
            int s0 = iv.x & 0xFFFF, s1 = iv.x >> 16;
            int s2 = iv.y & 0xFFFF, s3 = iv.y >> 16;
            int s4 = iv.z & 0xFFFF, s5 = iv.z >> 16;
            int s6 = iv.w & 0xFFFF, s7 = iv.w >> 16;
            f16x8 v0 = *(const f16x8*)(gp + (size_t)s0 * 16);
            f16x8 v1 = *(const f16x8*)(gp + (size_t)s1 * 16);
            f16x8 v2 = *(const f16x8*)(gp + (size_t)s2 * 16);
            f16x8 v3 = *(const f16x8*)(gp + (size_t)s3 * 16);
            f16x8 v4 = *(const f16x8*)(gp + (size_t)s4 * 16);
            f16x8 v5 = *(const f16x8*)(gp + (size_t)s5 * 16);
            f16x8 v6 = *(const f16x8*)(gp + (size_t)s6 * 16);
            f16x8 v7 = *(const f16x8*)(gp + (size_t)s7 * 16);
#pragma unroll
            for (int j = 0; j < 8; ++j)
                a[j] += (((float)v0[j] + (float)v1[j]) + ((float)v2[j] + (float)v3[j])) +
                        (((float)v4[j] + (float)v5[j]) + ((float)v6[j] + (float)v7[j]));
        }
        if (k + 4 <= n) {
            ushort4 s4v = *(const ushort4*)(lrow + k);
            f16x8 v0 = *(const f16x8*)(gp + (size_t)s4v.x * 16);
            f16x8 v1 = *(const f16x8*)(gp + (size_t)s4v.y * 16);
            f16x8 v2 = *(const f16x8*)(gp + (size_t)s4v.z * 16);
            f16x8 v3 = *(const f16x8*)(gp + (size_t)s4v.w * 16);
#pragma unroll
            for (int j = 0; j < 8; ++j)
                a[j] += ((float)v0[j] + (float)v1[j]) + ((float)v2[j] + (float)v3[j]);
            k += 4;
        }
        for (; k < n; ++k) {
            f16x8 v = *(const f16x8*)(gp + (size_t)lrow[k] * 16);
#pragma unroll
            for (int j = 0; j < 8; ++j) a[j] += (float)v[j];
        }

        const float* bp = b2 + nt * 16 + sub * 8;
        float4* op = (float4*)(out + (size_t)u * OUT_CH + nt * 16 + sub * 8);
        float4 o0, o1;
        o0.x = fmaxf(fmaf(du, a[0], bp[0]), 0.f);
        o0.y = fmaxf(fmaf(du, a[1], bp[1]), 0.f);
        o0.z = fmaxf(fmaf(du, a[2], bp[2]), 0.f);
        o0.w = fmaxf(fmaf(du, a[3], bp[3]), 0.f);
        o1.x = fmaxf(fmaf(du, a[4], bp[4]), 0.f);
        o1.y = fmaxf(fmaf(du, a[5], bp[5]), 0.f);
        o1.z = fmaxf(fmaf(du, a[6], bp[6]), 0.f);
        o1.w = fmaxf(fmaf(du, a[7], bp[7]), 0.f);
        op[0] = o0;
        op[1] = o1;
    }
}

// ---------------- launch ----------------

extern "C" void kernel_launch(void* const* d_in, const int* in_sizes, int n_in,
                              void* d_out, int out_size, void* d_ws, size_t ws_size,
                              hipStream_t stream) {
    const float* x  = (const float*)d_in[0];
    const int* ei   = (const int*)d_in[1];
    const float* W1 = (const float*)d_in[2];
    const float* b1 = (const float*)d_in[3];
    const float* W2 = (const float*)d_in[4];
    const float* b2 = (const float*)d_in[5];
    float* out = (float*)d_out;

    const int* src = ei;
    const int* dst = ei + N_EDGES;

    char* ws = (char*)d_ws;
    size_t off = 0;
    auto alloc = [&](size_t bytes) -> void* {
        off = (off + 255) & ~(size_t)255;
        void* p = ws + off;
        off += bytes;
        return p;
    };
    int*   zbuf      = (int*)alloc((size_t)(NBINS * 2) * 4);    // binCnt | binCursor
    int*   binCnt    = zbuf;
    int*   binCursor = zbuf + NBINS;
    u32*   ebuf      = (u32*)alloc((size_t)N_EDGES * 4);        // 3.2 MB
    int*   cnt       = (int*)alloc((size_t)N_NODES * 4);
    float* dis       = (float*)alloc((size_t)N_NODES * 4);
    u16*   bucket    = (u16*)alloc((size_t)N_NODES * CAP * 2);  // 6.4 MB
    f16*   W1sw      = (f16*)alloc((size_t)IN_CH * HID_CH * 2);
    f16*   W2sw      = (f16*)alloc((size_t)HID_CH * OUT_CH * 2);
    f16*   g1t       = (f16*)alloc((size_t)N_NODES * HID_CH * 2);  // tiled [8][N][16]
    f16*   g2t       = (f16*)alloc((size_t)N_NODES * OUT_CH * 2);  // tiled [4][N][16]

    hipMemsetAsync(zbuf, 0, (size_t)(NBINS * 2) * 4, stream);

    // 1. fused histogram + weight swizzle
    k_pre<<<PBLOCKS + SWZ_BLOCKS, 256, 0, stream>>>(dst, binCnt, W1, W2, W1sw, W2sw);
    // 2. place   3. build (+cnt +dis)
    k_place<<<PBLOCKS, 256, 0, stream>>>(src, dst, binCnt, binCursor, ebuf, N_EDGES);
    k_build<<<NBINS, 256, 0, stream>>>(ebuf, binCnt, cnt, dis, bucket, N_NODES);

    // 4. layer-1 GEMM: g1t = dis*(x @ W1), channel-tiled
    k_gemm1<<<(N_NODES + 63) / 64, 256, 0, stream>>>(x, W1sw, dis, g1t, N_NODES);

    // 5. fused pull1 + layer-2 GEMM (L2-resident tile-pair gathers)
    k_pullgemm<<<(N_NODES + 63) / 64, 256, 0, stream>>>(g1t, dis, b1, cnt, bucket,
                                                        W2sw, g2t);

    // 6. pull2 (L2-resident tile-pair gathers), fp32 out
    k_pull2<<<(N_NODES + 63) / 64, 256, 0, stream>>>(g2t, dis, b2, cnt, bucket, out);
}

// Round 4
// 211.934 us; speedup vs baseline: 1.0614x; 1.0614x over previous
//
#include <hip/hip_runtime.h>

#define N_NODES 50000
#define N_EDGES 800000
#define IN_CH 256
#define HID_CH 128
#define OUT_CH 64
#define CAP 64       // bucket slots/node; deg~Poisson(16), P(deg>=64) ~ 1e-18
#define NBINS 196    // ceil(N/256): bin = dst >> 8
#define PCHUNK 1600
#define PBLOCKS 500  // 500*1600 == N_EDGES
#define SWZ_ELEMS (IN_CH * HID_CH + HID_CH * OUT_CH)  // 40960
#define SWZ_BLOCKS (SWZ_ELEMS / 256)                  // 160

typedef _Float16 f16;
typedef _Float16 f16x8 __attribute__((ext_vector_type(8)));
typedef float f32x4 __attribute__((ext_vector_type(4)));
typedef unsigned short u16;
typedef unsigned int u32;

// ---------------- W -> MFMA B-fragment swizzle ----------------
template <int K, int N>
__device__ __forceinline__ void swz(const float* __restrict__ W, f16* __restrict__ Bsw,
                                    int idx) {
    constexpr int NTILES = N / 16;
    int j = idx & 7;
    int lane = (idx >> 3) & 63;
    int rest = idx >> 9;
    int nt = rest % NTILES;
    int ks = rest / NTILES;
    int k = ks * 32 + (lane >> 4) * 8 + j;
    int n = nt * 16 + (lane & 15);
    Bsw[idx] = (f16)W[(size_t)k * N + n];
}

// ---------------- local exclusive scan of binCnt ----------------
__device__ __forceinline__ void scan_local(const int* __restrict__ binCnt,
                                           int* sc, int* vv) {
    const int t = threadIdx.x;
    int v = (t < NBINS) ? binCnt[t] : 0;
    sc[t] = v; vv[t] = v;
    __syncthreads();
    for (int ofs = 1; ofs < 256; ofs <<= 1) {
        int add = (t >= ofs) ? sc[t - ofs] : 0;
        __syncthreads();
        sc[t] += add;
        __syncthreads();
    }
    // sc inclusive; exclusive = sc[t] - vv[t]
}

// ---------------- fused: dst-bin histogram + weight swizzle ----------------
__global__ __launch_bounds__(256) void k_pre(const int* __restrict__ dst,
                                             int* __restrict__ binCnt,
                                             const float* __restrict__ W1,
                                             const float* __restrict__ W2,
                                             f16* __restrict__ B1,
                                             f16* __restrict__ B2) {
    if ((int)blockIdx.x < PBLOCKS) {
        __shared__ int lcnt[NBINS];
        for (int i = threadIdx.x; i < NBINS; i += 256) lcnt[i] = 0;
        __syncthreads();
        int base = blockIdx.x * PCHUNK;
        for (int i = base + (int)threadIdx.x; i < base + PCHUNK; i += 256)
            atomicAdd(&lcnt[dst[i] >> 8], 1);
        __syncthreads();
        for (int i = threadIdx.x; i < NBINS; i += 256)
            if (lcnt[i]) atomicAdd(&binCnt[i], lcnt[i]);
        return;
    }
    int idx = ((int)blockIdx.x - PBLOCKS) * 256 + threadIdx.x;
    if (idx < IN_CH * HID_CH) {
        swz<IN_CH, HID_CH>(W1, B1, idx);
    } else {
        idx -= IN_CH * HID_CH;
        if (idx < HID_CH * OUT_CH) swz<HID_CH, OUT_CH>(W2, B2, idx);
    }
}

// ---------------- place packed (dst<<16|src) codes into bin segments ----------------
__global__ __launch_bounds__(256) void k_place(const int* __restrict__ src,
                                               const int* __restrict__ dst,
                                               const int* __restrict__ binCnt,
                                               int* __restrict__ binCursor,
                                               u32* __restrict__ ebuf, int E) {
    __shared__ u32 codes[PCHUNK];
    __shared__ int sc[256], vv[256];
    __shared__ int lcnt[NBINS], lbase[NBINS], lcur[NBINS];
    scan_local(binCnt, sc, vv);
    for (int i = threadIdx.x; i < NBINS; i += 256) lcnt[i] = 0;
    __syncthreads();
    int base = blockIdx.x * PCHUNK;
    int m = min(PCHUNK, E - base);
    for (int j = threadIdx.x; j < m; j += 256) {
        u32 d = (u32)dst[base + j];
        codes[j] = (d << 16) | (u32)src[base + j];
        atomicAdd(&lcnt[d >> 8], 1);
    }
    __syncthreads();
    for (int i = threadIdx.x; i < NBINS; i += 256) {
        lbase[i] = (sc[i] - vv[i]) + atomicAdd(&binCursor[i], lcnt[i]);
        lcur[i] = 0;
    }
    __syncthreads();
    for (int j = threadIdx.x; j < m; j += 256) {
        u32 c = codes[j];
        int b = c >> 24;
        int p = atomicAdd(&lcur[b], 1);
        ebuf[lbase[b] + p] = c;
    }
}

// ---------------- per-half-bin CSR build in LDS + cnt + dis ----------------
// 392 blocks (2 per bin, 128 nodes each): 196-block grid left half the CUs idle.
__global__ __launch_bounds__(256) void k_build(const u32* __restrict__ ebuf,
                                               const int* __restrict__ binCnt,
                                               int* __restrict__ cnt,
                                               float* __restrict__ dis,
                                               u16* __restrict__ bucket, int N) {
    __shared__ int sc[256], vv[256];
    __shared__ int lcnt[128];
    __shared__ u16 lbuck[128 * CAP];   // 16 KB
    scan_local(binCnt, sc, vv);
    int t = threadIdx.x;
    if (t < 128) lcnt[t] = 0;
    __syncthreads();
    int b = blockIdx.x >> 1;       // bin
    int half = blockIdx.x & 1;     // node-half within bin
    int s = sc[b] - vv[b];
    int e = sc[b];
    for (int i = s + t; i < e; i += 256) {
        u32 c = ebuf[i];
        int local = (c >> 16) & 255;
        if ((local >> 7) == half) {
            int l = local & 127;
            int p = atomicAdd(&lcnt[l], 1);
            if (p < CAP) lbuck[l * CAP + p] = (u16)(c & 0xFFFFu);
        }
    }
    __syncthreads();
    int nodeBase = (b << 8) + (half << 7);
    if (t < 128 && nodeBase + t < N) {
        cnt[nodeBase + t] = lcnt[t];
        dis[nodeBase + t] = rsqrtf((float)lcnt[t] + 1.0f);
    }
    // write only the 16B chunks that hold live entries
    const uint4* lsrc = (const uint4*)lbuck;
    uint4* gdst = (uint4*)(bucket + (size_t)nodeBase * CAP);
    for (int idx = t; idx < 128 * CAP / 8; idx += 256) {
        int row = idx >> 3;
        int chunk = idx & 7;
        if (nodeBase + row < N && (chunk << 3) < lcnt[row]) gdst[idx] = lsrc[idx];
    }
}

// ---------------- MFMA fp16 GEMM layer1: g1 = dis[m]*(x @ W1), row-major out ----
__global__ __launch_bounds__(256) void k_gemm1(const float* __restrict__ A,
                                               const f16* __restrict__ Bsw,
                                               const float* __restrict__ dis,
                                               f16* __restrict__ C, int M) {
    constexpr int K = IN_CH, N = HID_CH;
    constexpr int KSTEPS = K / 32, NTILES = N / 16;
    const int tid = threadIdx.x;
    const int wave = tid >> 6, lane = tid & 63;
    const int quad = lane >> 4, l16 = lane & 15;
    int row = blockIdx.x * 64 + wave * 16 + l16;
    const int rowc = row < M ? row : M - 1;

    f32x4 acc[NTILES];
#pragma unroll
    for (int t = 0; t < NTILES; ++t) acc[t] = (f32x4){0.f, 0.f, 0.f, 0.f};

#pragma unroll
    for (int ks = 0; ks < KSTEPS; ++ks) {
        f16x8 afrag;
        const float4* p = (const float4*)(A + (size_t)rowc * K + ks * 32 + quad * 8);
        float4 v0 = p[0], v1 = p[1];
        afrag[0] = (f16)v0.x; afrag[1] = (f16)v0.y;
        afrag[2] = (f16)v0.z; afrag[3] = (f16)v0.w;
        afrag[4] = (f16)v1.x; afrag[5] = (f16)v1.y;
        afrag[6] = (f16)v1.z; afrag[7] = (f16)v1.w;
#pragma unroll
        for (int t = 0; t < NTILES; ++t) {
            f16x8 bfrag = *(const f16x8*)(Bsw + (((size_t)ks * NTILES + t) * 64 + lane) * 8);
            acc[t] = __builtin_amdgcn_mfma_f32_16x16x32_f16(afrag, bfrag, acc[t], 0, 0, 0);
        }
    }

    int rbase = blockIdx.x * 64 + wave * 16 + quad * 4;
#pragma unroll
    for (int r = 0; r < 4; ++r) {
        int gr = rbase + r;
        if (gr < M) {
            float d = dis[gr];
#pragma unroll
            for (int t = 0; t < NTILES; ++t)
                C[(size_t)gr * N + t * 16 + l16] = (f16)(acc[t][r] * d);
        }
    }
}

// ---------------- fused pull1 + gemm2, 1024-thread blocks ----------------
// Phase A (gather, all 16 waves): every node gets its own 16-lane group —
//   2 blocks/CU x 16 waves = 32 waves/CU vs 12 before (phase A is latency-bound).
//   agg[u,c] = relu( du*(g1[u,c] + sum_s g1[s,c]) + b1[c] ) -> LDS (g1 prescaled).
// Phase B (waves 0..3): g2[u,:] = dis[u] * (agg[u,:] @ W2), 64x64 MFMA tile.
__global__ __launch_bounds__(1024, 8) void k_pullgemm(const f16* __restrict__ g1,
                                                      const float* __restrict__ dis,
                                                      const float* __restrict__ b1,
                                                      const int* __restrict__ cnt,
                                                      const u16* __restrict__ bucket,
                                                      const f16* __restrict__ B2sw,
                                                      f16* __restrict__ g2) {
    constexpr int LDSW = HID_CH + 8;       // 136 f16 = 272 B row stride
    __shared__ f16 aggl[64 * LDSW];        // 17.4 KB
    const int tid = threadIdx.x;
    const int sub = tid & 15;              // channel octet 0..15
    const int nl = tid >> 4;               // node slot 0..63
    const int blockBase = (int)blockIdx.x * 64;
    const int u = blockBase + nl;

    f16x8 o;
    if (u < N_NODES) {
        const f16* gp = g1 + sub * 8;
        f16x8 sv = *(const f16x8*)(gp + (size_t)u * HID_CH);
        float a[8];
#pragma unroll
        for (int j = 0; j < 8; ++j) a[j] = (float)sv[j];

        int n = cnt[u];
        if (n > CAP) n = CAP;
        const u16* row = bucket + u * CAP;

        int k = 0;
        for (; k + 8 <= n; k += 8) {
            uint4 iv = *(const uint4*)(row + k);
            int s0 = iv.x & 0xFFFF, s1 = iv.x >> 16;
            int s2 = iv.y & 0xFFFF, s3 = iv.y >> 16;
            int s4 = iv.z & 0xFFFF, s5 = iv.z >> 16;
            int s6 = iv.w & 0xFFFF, s7 = iv.w >> 16;
            f16x8 v0 = *(const f16x8*)(gp + (size_t)s0 * HID_CH);
            f16x8 v1 = *(const f16x8*)(gp + (size_t)s1 * HID_CH);
            f16x8 v2 = *(const f16x8*)(gp + (size_t)s2 * HID_CH);
            f16x8 v3 = *(const f16x8*)(gp + (size_t)s3 * HID_CH);
            f16x8 v4 = *(const f16x8*)(gp + (size_t)s4 * HID_CH);
            f16x8 v5 = *(const f16x8*)(gp + (size_t)s5 * HID_CH);
            f16x8 v6 = *(const f16x8*)(gp + (size_t)s6 * HID_CH);
            f16x8 v7 = *(const f16x8*)(gp + (size_t)s7 * HID_CH);
#pragma unroll
            for (int j = 0; j < 8; ++j)
                a[j] += (((float)v0[j] + (float)v1[j]) + ((float)v2[j] + (float)v3[j])) +
                        (((float)v4[j] + (float)v5[j]) + ((float)v6[j] + (float)v7[j]));
        }
        if (k + 4 <= n) {
            ushort4 s4v = *(const ushort4*)(row + k);
            f16x8 v0 = *(const f16x8*)(gp + (size_t)s4v.x * HID_CH);
            f16x8 v1 = *(const f16x8*)(gp + (size_t)s4v.y * HID_CH);
            f16x8 v2 = *(const f16x8*)(gp + (size_t)s4v.z * HID_CH);
            f16x8 v3 = *(const f16x8*)(gp + (size_t)s4v.w * HID_CH);
#pragma unroll
            for (int j = 0; j < 8; ++j)
                a[j] += ((float)v0[j] + (float)v1[j]) + ((float)v2[j] + (float)v3[j]);
            k += 4;
        }
        for (; k < n; ++k) {
            f16x8 v = *(const f16x8*)(gp + (size_t)row[k] * HID_CH);
#pragma unroll
            for (int j = 0; j < 8; ++j) a[j] += (float)v[j];
        }

        float du = dis[u];
        const float4* b1p = (const float4*)(b1 + sub * 8);
        float4 bb0 = b1p[0], bb1 = b1p[1];
        float bv[8] = {bb0.x, bb0.y, bb0.z, bb0.w, bb1.x, bb1.y, bb1.z, bb1.w};
#pragma unroll
        for (int j = 0; j < 8; ++j) {
            float t = fmaf(du, a[j], bv[j]);
            o[j] = (f16)(t > 0.f ? t : 0.f);   // relu(cvt) == cvt(relu) for f16
        }
    } else {
#pragma unroll
        for (int j = 0; j < 8; ++j) o[j] = (f16)0;
    }
    *(f16x8*)(aggl + (size_t)nl * LDSW + sub * 8) = o;
    __syncthreads();

    // ---- phase B: waves 0..3 run the 64x64 MFMA tile, K=128, A from LDS ----
    if (tid < 256) {
        constexpr int KSTEPS = HID_CH / 32, NTILES = OUT_CH / 16;
        const int wave = tid >> 6, lane = tid & 63;
        const int quad = lane >> 4, l16 = lane & 15;
        const int lrowA = wave * 16 + l16;

        f32x4 acc[NTILES];
#pragma unroll
        for (int t = 0; t < NTILES; ++t) acc[t] = (f32x4){0.f, 0.f, 0.f, 0.f};

#pragma unroll
        for (int ks = 0; ks < KSTEPS; ++ks) {
            f16x8 afrag = *(const f16x8*)(aggl + (size_t)lrowA * LDSW + ks * 32 + quad * 8);
#pragma unroll
            for (int t = 0; t < NTILES; ++t) {
                f16x8 bfrag = *(const f16x8*)(B2sw + (((size_t)ks * NTILES + t) * 64 + lane) * 8);
                acc[t] = __builtin_amdgcn_mfma_f32_16x16x32_f16(afrag, bfrag, acc[t], 0, 0, 0);
            }
        }

        int rbase = blockBase + wave * 16 + quad * 4;
#pragma unroll
        for (int r = 0; r < 4; ++r) {
            int gr = rbase + r;
            if (gr < N_NODES) {
                float d = dis[gr];
#pragma unroll
                for (int t = 0; t < NTILES; ++t)
                    g2[(size_t)gr * OUT_CH + t * 16 + l16] = (f16)(acc[t][r] * d);
            }
        }
    }
}

// ---------------- pull2: 8 lanes/node, f16x8 — 8 independent node-chains/wave ----------------
// out[u,c] = relu( du*(g2[u,c] + sum g2[s,c]) + b2[c] ), fp32.
__global__ __launch_bounds__(256) void k_pull2(const f16* __restrict__ g2,
                                               const float* __restrict__ dis,
                                               const float* __restrict__ b2,
                                               const int* __restrict__ cnt,
                                               const u16* __restrict__ bucket,
                                               float* __restrict__ out) {
    int gtid = blockIdx.x * 256 + threadIdx.x;
    int u = gtid >> 3;
    int sub = gtid & 7;
    if (u >= N_NODES) return;
    const f16* gp = g2 + sub * 8;

    f16x8 sv = *(const f16x8*)(gp + (size_t)u * OUT_CH);
    float a[8];
#pragma unroll
    for (int j = 0; j < 8; ++j) a[j] = (float)sv[j];

    int n = cnt[u];
    if (n > CAP) n = CAP;
    const u16* row = bucket + u * CAP;

    int k = 0;
    for (; k + 8 <= n; k += 8) {
        uint4 iv = *(const uint4*)(row + k);
        int s0 = iv.x & 0xFFFF, s1 = iv.x >> 16;
        int s2 = iv.y & 0xFFFF, s3 = iv.y >> 16;
        int s4 = iv.z & 0xFFFF, s5 = iv.z >> 16;
        int s6 = iv.w & 0xFFFF, s7 = iv.w >> 16;
        f16x8 v0 = *(const f16x8*)(gp + (size_t)s0 * OUT_CH);
        f16x8 v1 = *(const f16x8*)(gp + (size_t)s1 * OUT_CH);
        f16x8 v2 = *(const f16x8*)(gp + (size_t)s2 * OUT_CH);
        f16x8 v3 = *(const f16x8*)(gp + (size_t)s3 * OUT_CH);
        f16x8 v4 = *(const f16x8*)(gp + (size_t)s4 * OUT_CH);
        f16x8 v5 = *(const f16x8*)(gp + (size_t)s5 * OUT_CH);
        f16x8 v6 = *(const f16x8*)(gp + (size_t)s6 * OUT_CH);
        f16x8 v7 = *(const f16x8*)(gp + (size_t)s7 * OUT_CH);
#pragma unroll
        for (int j = 0; j < 8; ++j)
            a[j] += (((float)v0[j] + (float)v1[j]) + ((float)v2[j] + (float)v3[j])) +
                    (((float)v4[j] + (float)v5[j]) + ((float)v6[j] + (float)v7[j]));
    }
    if (k + 4 <= n) {
        ushort4 s4v = *(const ushort4*)(row + k);
        f16x8 v0 = *(const f16x8*)(gp + (size_t)s4v.x * OUT_CH);
        f16x8 v1 = *(const f16x8*)(gp + (size_t)s4v.y * OUT_CH);
        f16x8 v2 = *(const f16x8*)(gp + (size_t)s4v.z * OUT_CH);
        f16x8 v3 = *(const f16x8*)(gp + (size_t)s4v.w * OUT_CH);
#pragma unroll
        for (int j = 0; j < 8; ++j)
            a[j] += ((float)v0[j] + (float)v1[j]) + ((float)v2[j] + (float)v3[j]);
        k += 4;
    }
    for (; k < n; ++k) {
        f16x8 v = *(const f16x8*)(gp + (size_t)row[k] * OUT_CH);
#pragma unroll
        for (int j = 0; j < 8; ++j) a[j] += (float)v[j];
    }

    float du = dis[u];
    float4* op = (float4*)(out + (size_t)u * OUT_CH + sub * 8);
    float4 o0, o1;
    o0.x = fmaxf(fmaf(du, a[0], b2[sub * 8 + 0]), 0.f);
    o0.y = fmaxf(fmaf(du, a[1], b2[sub * 8 + 1]), 0.f);
    o0.z = fmaxf(fmaf(du, a[2], b2[sub * 8 + 2]), 0.f);
    o0.w = fmaxf(fmaf(du, a[3], b2[sub * 8 + 3]), 0.f);
    o1.x = fmaxf(fmaf(du, a[4], b2[sub * 8 + 4]), 0.f);
    o1.y = fmaxf(fmaf(du, a[5], b2[sub * 8 + 5]), 0.f);
    o1.z = fmaxf(fmaf(du, a[6], b2[sub * 8 + 6]), 0.f);
    o1.w = fmaxf(fmaf(du, a[7], b2[sub * 8 + 7]), 0.f);
    op[0] = o0;
    op[1] = o1;
}

// ---------------- launch ----------------

extern "C" void kernel_launch(void* const* d_in, const int* in_sizes, int n_in,
                              void* d_out, int out_size, void* d_ws, size_t ws_size,
                              hipStream_t stream) {
    const float* x  = (const float*)d_in[0];
    const int* ei   = (const int*)d_in[1];
    const float* W1 = (const float*)d_in[2];
    const float* b1 = (const float*)d_in[3];
    const float* W2 = (const float*)d_in[4];
    const float* b2 = (const float*)d_in[5];
    float* out = (float*)d_out;

    const int* src = ei;
    const int* dst = ei + N_EDGES;

    char* ws = (char*)d_ws;
    size_t off = 0;
    auto alloc = [&](size_t bytes) -> void* {
        off = (off + 255) & ~(size_t)255;
        void* p = ws + off;
        off += bytes;
        return p;
    };
    int*   zbuf      = (int*)alloc((size_t)(NBINS * 2) * 4);    // binCnt | binCursor
    int*   binCnt    = zbuf;
    int*   binCursor = zbuf + NBINS;
    u32*   ebuf      = (u32*)alloc((size_t)N_EDGES * 4);        // 3.2 MB
    int*   cnt       = (int*)alloc((size_t)N_NODES * 4);
    float* dis       = (float*)alloc((size_t)N_NODES * 4);
    u16*   bucket    = (u16*)alloc((size_t)N_NODES * CAP * 2);  // 6.4 MB
    f16*   W1sw      = (f16*)alloc((size_t)IN_CH * HID_CH * 2);
    f16*   W2sw      = (f16*)alloc((size_t)HID_CH * OUT_CH * 2);
    f16*   g1        = (f16*)alloc((size_t)N_NODES * HID_CH * 2);  // prescaled, row-major
    f16*   g2        = (f16*)alloc((size_t)N_NODES * OUT_CH * 2);  // prescaled, row-major

    hipMemsetAsync(zbuf, 0, (size_t)(NBINS * 2) * 4, stream);

    // 1. fused histogram + weight swizzle
    k_pre<<<PBLOCKS + SWZ_BLOCKS, 256, 0, stream>>>(dst, binCnt, W1, W2, W1sw, W2sw);
    // 2. place   3. build (half-bins, +cnt +dis)
    k_place<<<PBLOCKS, 256, 0, stream>>>(src, dst, binCnt, binCursor, ebuf, N_EDGES);
    k_build<<<NBINS * 2, 256, 0, stream>>>(ebuf, binCnt, cnt, dis, bucket, N_NODES);

    // 4. layer-1 GEMM: g1 = dis*(x @ W1), row-major
    k_gemm1<<<(N_NODES + 63) / 64, 256, 0, stream>>>(x, W1sw, dis, g1, N_NODES);

    // 5. fused pull1 + layer-2 GEMM, 1024-thread blocks for gather occupancy
    k_pullgemm<<<(N_NODES + 63) / 64, 1024, 0, stream>>>(g1, dis, b1, cnt, bucket,
                                                         W2sw, g2);

    // 6. pull2: out = relu(du*(g2[u]+sum g2[s]) + b2), fp32
    k_pull2<<<(N_NODES * 8 + 255) / 256, 256, 0, stream>>>(g2, dis, b2, cnt, bucket, out);
}

// Round 5
// 199.393 us; speedup vs baseline: 1.1282x; 1.0629x over previous
//
#include <hip/hip_runtime.h>

#define N_NODES 50000
#define N_EDGES 800000
#define IN_CH 256
#define HID_CH 128
#define OUT_CH 64
#define CAP 64       // bucket slots/node; deg~Poisson(16), P(deg>=64) ~ 1e-18
#define NBINS 196    // ceil(N/256): bin = dst >> 8
#define PCHUNK 3200
#define PBLOCKS 250  // 250*3200 == N_EDGES
#define SWZ_ELEMS (IN_CH * HID_CH + HID_CH * OUT_CH)  // 40960
#define SWZ_BLOCKS (SWZ_ELEMS / 256)                  // 160

typedef _Float16 f16;
typedef _Float16 f16x8 __attribute__((ext_vector_type(8)));
typedef float f32x4 __attribute__((ext_vector_type(4)));
typedef unsigned short u16;
typedef unsigned int u32;

// ---------------- W -> MFMA B-fragment swizzle ----------------
template <int K, int N>
__device__ __forceinline__ void swz(const float* __restrict__ W, f16* __restrict__ Bsw,
                                    int idx) {
    constexpr int NTILES = N / 16;
    int j = idx & 7;
    int lane = (idx >> 3) & 63;
    int rest = idx >> 9;
    int nt = rest % NTILES;
    int ks = rest / NTILES;
    int k = ks * 32 + (lane >> 4) * 8 + j;
    int n = nt * 16 + (lane & 15);
    Bsw[idx] = (f16)W[(size_t)k * N + n];
}

// ---------------- local exclusive scan of binCnt ----------------
__device__ __forceinline__ void scan_local(const int* __restrict__ binCnt,
                                           int* sc, int* vv) {
    const int t = threadIdx.x;
    int v = (t < NBINS) ? binCnt[t] : 0;
    sc[t] = v; vv[t] = v;
    __syncthreads();
    for (int ofs = 1; ofs < 256; ofs <<= 1) {
        int add = (t >= ofs) ? sc[t - ofs] : 0;
        __syncthreads();
        sc[t] += add;
        __syncthreads();
    }
    // sc inclusive; exclusive = sc[t] - vv[t]
}

// ---------------- fused: dst-bin histogram + weight swizzle ----------------
__global__ __launch_bounds__(256) void k_pre(const int* __restrict__ dst,
                                             int* __restrict__ binCnt,
                                             const float* __restrict__ W1,
                                             const float* __restrict__ W2,
                                             f16* __restrict__ B1,
                                             f16* __restrict__ B2) {
    if ((int)blockIdx.x < PBLOCKS) {
        __shared__ int lcnt[NBINS];
        for (int i = threadIdx.x; i < NBINS; i += 256) lcnt[i] = 0;
        __syncthreads();
        int base = blockIdx.x * PCHUNK;
        for (int i = base + (int)threadIdx.x; i < base + PCHUNK; i += 256)
            atomicAdd(&lcnt[dst[i] >> 8], 1);
        __syncthreads();
        for (int i = threadIdx.x; i < NBINS; i += 256)
            if (lcnt[i]) atomicAdd(&binCnt[i], lcnt[i]);
        return;
    }
    int idx = ((int)blockIdx.x - PBLOCKS) * 256 + threadIdx.x;
    if (idx < IN_CH * HID_CH) {
        swz<IN_CH, HID_CH>(W1, B1, idx);
    } else {
        idx -= IN_CH * HID_CH;
        if (idx < HID_CH * OUT_CH) swz<HID_CH, OUT_CH>(W2, B2, idx);
    }
}

// ---------------- place packed (dst<<16|src) codes into bin segments ----------------
__global__ __launch_bounds__(256) void k_place(const int* __restrict__ src,
                                               const int* __restrict__ dst,
                                               const int* __restrict__ binCnt,
                                               int* __restrict__ binCursor,
                                               u32* __restrict__ ebuf, int E) {
    __shared__ u32 codes[PCHUNK];
    __shared__ int sc[256], vv[256];
    __shared__ int lcnt[NBINS], lbase[NBINS], lcur[NBINS];
    scan_local(binCnt, sc, vv);
    for (int i = threadIdx.x; i < NBINS; i += 256) lcnt[i] = 0;
    __syncthreads();
    int base = blockIdx.x * PCHUNK;
    int m = min(PCHUNK, E - base);
    for (int j = threadIdx.x; j < m; j += 256) {
        u32 d = (u32)dst[base + j];
        codes[j] = (d << 16) | (u32)src[base + j];
        atomicAdd(&lcnt[d >> 8], 1);
    }
    __syncthreads();
    for (int i = threadIdx.x; i < NBINS; i += 256) {
        lbase[i] = (sc[i] - vv[i]) + atomicAdd(&binCursor[i], lcnt[i]);
        lcur[i] = 0;
    }
    __syncthreads();
    for (int j = threadIdx.x; j < m; j += 256) {
        u32 c = codes[j];
        int b = c >> 24;
        int p = atomicAdd(&lcur[b], 1);
        ebuf[lbase[b] + p] = c;
    }
}

// ---------------- per-bin CSR build in LDS + cnt + dis ----------------
__global__ __launch_bounds__(256) void k_build(const u32* __restrict__ ebuf,
                                               const int* __restrict__ binCnt,
                                               int* __restrict__ cnt,
                                               float* __restrict__ dis,
                                               u16* __restrict__ bucket, int N) {
    __shared__ int sc[256], vv[256];
    __shared__ int lcnt[256];
    __shared__ u16 lbuck[256 * CAP];   // 32 KB
    scan_local(binCnt, sc, vv);
    int t = threadIdx.x;
    lcnt[t] = 0;
    __syncthreads();
    int b = blockIdx.x;
    int s = sc[b] - vv[b];
    int e = sc[b];
    for (int i = s + t; i < e; i += 256) {
        u32 c = ebuf[i];
        int local = (c >> 16) & 255;
        int p = atomicAdd(&lcnt[local], 1);
        if (p < CAP) lbuck[local * CAP + p] = (u16)(c & 0xFFFFu);
    }
    __syncthreads();
    int nodeBase = b << 8;
    if (nodeBase + t < N) {
        cnt[nodeBase + t] = lcnt[t];
        dis[nodeBase + t] = rsqrtf((float)lcnt[t] + 1.0f);
    }
    // write only the 16B chunks that hold live entries
    const uint4* lsrc = (const uint4*)lbuck;
    uint4* gdst = (uint4*)(bucket + (size_t)nodeBase * CAP);
    for (int idx = t; idx < 256 * CAP / 8; idx += 256) {
        int row = idx >> 3;
        int chunk = idx & 7;
        if (nodeBase + row < N && (chunk << 3) < lcnt[row]) gdst[idx] = lsrc[idx];
    }
}

// ---------------- MFMA fp16 GEMM layer1: g1 = dis[m]*(x @ W1), row-major out ----
__global__ __launch_bounds__(256) void k_gemm1(const float* __restrict__ A,
                                               const f16* __restrict__ Bsw,
                                               const float* __restrict__ dis,
                                               f16* __restrict__ C, int M) {
    constexpr int K = IN_CH, N = HID_CH;
    constexpr int KSTEPS = K / 32, NTILES = N / 16;
    const int tid = threadIdx.x;
    const int wave = tid >> 6, lane = tid & 63;
    const int quad = lane >> 4, l16 = lane & 15;
    int row = blockIdx.x * 64 + wave * 16 + l16;
    const int rowc = row < M ? row : M - 1;

    f32x4 acc[NTILES];
#pragma unroll
    for (int t = 0; t < NTILES; ++t) acc[t] = (f32x4){0.f, 0.f, 0.f, 0.f};

#pragma unroll
    for (int ks = 0; ks < KSTEPS; ++ks) {
        f16x8 afrag;
        const float4* p = (const float4*)(A + (size_t)rowc * K + ks * 32 + quad * 8);
        float4 v0 = p[0], v1 = p[1];
        afrag[0] = (f16)v0.x; afrag[1] = (f16)v0.y;
        afrag[2] = (f16)v0.z; afrag[3] = (f16)v0.w;
        afrag[4] = (f16)v1.x; afrag[5] = (f16)v1.y;
        afrag[6] = (f16)v1.z; afrag[7] = (f16)v1.w;
#pragma unroll
        for (int t = 0; t < NTILES; ++t) {
            f16x8 bfrag = *(const f16x8*)(Bsw + (((size_t)ks * NTILES + t) * 64 + lane) * 8);
            acc[t] = __builtin_amdgcn_mfma_f32_16x16x32_f16(afrag, bfrag, acc[t], 0, 0, 0);
        }
    }

    int rbase = blockIdx.x * 64 + wave * 16 + quad * 4;
#pragma unroll
    for (int r = 0; r < 4; ++r) {
        int gr = rbase + r;
        if (gr < M) {
            float d = dis[gr];
#pragma unroll
            for (int t = 0; t < NTILES; ++t)
                C[(size_t)gr * N + t * 16 + l16] = (f16)(acc[t][r] * d);
        }
    }
}

// ---------------- fused pull1 + gemm2, 512-thread blocks ----------------
// Phase A (gather, 8 waves): 32 nodes/pass x 2 passes, 16 lanes/node.
//   512t (no reg-cap launch_bounds) -> ~3 blocks/CU co-resident = ~24 waves/CU
//   vs 12 at 256t: 2x outstanding gather chains for the latency-bound phase.
//   agg[u,c] = relu( du*(g1[u,c] + sum_s g1[s,c]) + b1[c] ) -> LDS (g1 prescaled).
// Phase B (all 8 waves): 64x64 MFMA tile split 2 ways in N: wave = (rgrp, ntp),
//   each wave 16 rows x 2 n-tiles, K=128 from LDS.
__global__ __launch_bounds__(512) void k_pullgemm(const f16* __restrict__ g1,
                                                  const float* __restrict__ dis,
                                                  const float* __restrict__ b1,
                                                  const int* __restrict__ cnt,
                                                  const u16* __restrict__ bucket,
                                                  const f16* __restrict__ B2sw,
                                                  f16* __restrict__ g2) {
    constexpr int LDSW = HID_CH + 8;       // 136 f16 = 272 B row stride
    __shared__ f16 aggl[64 * LDSW];        // 17.4 KB
    const int tid = threadIdx.x;
    const int sub = tid & 15;              // channel octet 0..15
    const int nl = tid >> 4;               // node slot 0..31
    const int blockBase = (int)blockIdx.x * 64;

    // hoist bias (sub fixed per thread)
    const float4* b1p = (const float4*)(b1 + sub * 8);
    float4 bb0 = b1p[0], bb1 = b1p[1];
    float bv[8] = {bb0.x, bb0.y, bb0.z, bb0.w, bb1.x, bb1.y, bb1.z, bb1.w};

    // ---- phase A: 2 passes of 32 nodes ----
    for (int it = 0; it < 2; ++it) {
        int lrow = it * 32 + nl;
        int u = blockBase + lrow;
        f16x8 o;
        if (u < N_NODES) {
            const f16* gp = g1 + sub * 8;
            f16x8 sv = *(const f16x8*)(gp + (size_t)u * HID_CH);
            float a[8];
#pragma unroll
            for (int j = 0; j < 8; ++j) a[j] = (float)sv[j];

            int n = cnt[u];
            if (n > CAP) n = CAP;
            const u16* row = bucket + u * CAP;

            int k = 0;
            for (; k + 8 <= n; k += 8) {
                uint4 iv = *(const uint4*)(row + k);
                int s0 = iv.x & 0xFFFF, s1 = iv.x >> 16;
                int s2 = iv.y & 0xFFFF, s3 = iv.y >> 16;
                int s4 = iv.z & 0xFFFF, s5 = iv.z >> 16;
                int s6 = iv.w & 0xFFFF, s7 = iv.w >> 16;
                f16x8 v0 = *(const f16x8*)(gp + (size_t)s0 * HID_CH);
                f16x8 v1 = *(const f16x8*)(gp + (size_t)s1 * HID_CH);
                f16x8 v2 = *(const f16x8*)(gp + (size_t)s2 * HID_CH);
                f16x8 v3 = *(const f16x8*)(gp + (size_t)s3 * HID_CH);
                f16x8 v4 = *(const f16x8*)(gp + (size_t)s4 * HID_CH);
                f16x8 v5 = *(const f16x8*)(gp + (size_t)s5 * HID_CH);
                f16x8 v6 = *(const f16x8*)(gp + (size_t)s6 * HID_CH);
                f16x8 v7 = *(const f16x8*)(gp + (size_t)s7 * HID_CH);
#pragma unroll
                for (int j = 0; j < 8; ++j)
                    a[j] += (((float)v0[j] + (float)v1[j]) + ((float)v2[j] + (float)v3[j])) +
                            (((float)v4[j] + (float)v5[j]) + ((float)v6[j] + (float)v7[j]));
            }
            if (k + 4 <= n) {
                ushort4 s4v = *(const ushort4*)(row + k);
                f16x8 v0 = *(const f16x8*)(gp + (size_t)s4v.x * HID_CH);
                f16x8 v1 = *(const f16x8*)(gp + (size_t)s4v.y * HID_CH);
                f16x8 v2 = *(const f16x8*)(gp + (size_t)s4v.z * HID_CH);
                f16x8 v3 = *(const f16x8*)(gp + (size_t)s4v.w * HID_CH);
#pragma unroll
                for (int j = 0; j < 8; ++j)
                    a[j] += ((float)v0[j] + (float)v1[j]) + ((float)v2[j] + (float)v3[j]);
                k += 4;
            }
            for (; k < n; ++k) {
                f16x8 v = *(const f16x8*)(gp + (size_t)row[k] * HID_CH);
#pragma unroll
                for (int j = 0; j < 8; ++j) a[j] += (float)v[j];
            }

            float du = dis[u];
#pragma unroll
            for (int j = 0; j < 8; ++j) {
                float t = fmaf(du, a[j], bv[j]);
                o[j] = (f16)(t > 0.f ? t : 0.f);   // relu(cvt) == cvt(relu) for f16
            }
        } else {
#pragma unroll
            for (int j = 0; j < 8; ++j) o[j] = (f16)0;
        }
        *(f16x8*)(aggl + (size_t)lrow * LDSW + sub * 8) = o;
    }
    __syncthreads();

    // ---- phase B: 8 waves, each 16 rows x 2 n-tiles, K=128 from LDS ----
    {
        constexpr int KSTEPS = HID_CH / 32;
        const int wave = tid >> 6, lane = tid & 63;
        const int quad = lane >> 4, l16 = lane & 15;
        const int rgrp = (wave & 3) * 16;     // row group
        const int ntp = wave >> 2;            // n-tile pair (0: tiles 0-1, 1: tiles 2-3)
        const int lrowA = rgrp + l16;

        f32x4 acc[2];
        acc[0] = (f32x4){0.f, 0.f, 0.f, 0.f};
        acc[1] = (f32x4){0.f, 0.f, 0.f, 0.f};

#pragma unroll
        for (int ks = 0; ks < KSTEPS; ++ks) {
            f16x8 afrag = *(const f16x8*)(aggl + (size_t)lrowA * LDSW + ks * 32 + quad * 8);
#pragma unroll
            for (int t = 0; t < 2; ++t) {
                int nt = ntp * 2 + t;
                f16x8 bfrag = *(const f16x8*)(B2sw + (((size_t)ks * 4 + nt) * 64 + lane) * 8);
                acc[t] = __builtin_amdgcn_mfma_f32_16x16x32_f16(afrag, bfrag, acc[t], 0, 0, 0);
            }
        }

        int rbase = blockBase + rgrp + quad * 4;
#pragma unroll
        for (int r = 0; r < 4; ++r) {
            int gr = rbase + r;
            if (gr < N_NODES) {
                float d = dis[gr];
#pragma unroll
                for (int t = 0; t < 2; ++t) {
                    int nt = ntp * 2 + t;
                    g2[(size_t)gr * OUT_CH + nt * 16 + l16] = (f16)(acc[t][r] * d);
                }
            }
        }
    }
}

// ---------------- pull2: 8 lanes/node, f16x8 — 8 independent node-chains/wave ----------------
// out[u,c] = relu( du*(g2[u,c] + sum g2[s,c]) + b2[c] ), fp32.
__global__ __launch_bounds__(256) void k_pull2(const f16* __restrict__ g2,
                                               const float* __restrict__ dis,
                                               const float* __restrict__ b2,
                                               const int* __restrict__ cnt,
                                               const u16* __restrict__ bucket,
                                               float* __restrict__ out) {
    int gtid = blockIdx.x * 256 + threadIdx.x;
    int u = gtid >> 3;
    int sub = gtid & 7;
    if (u >= N_NODES) return;
    const f16* gp = g2 + sub * 8;

    f16x8 sv = *(const f16x8*)(gp + (size_t)u * OUT_CH);
    float a[8];
#pragma unroll
    for (int j = 0; j < 8; ++j) a[j] = (float)sv[j];

    int n = cnt[u];
    if (n > CAP) n = CAP;
    const u16* row = bucket + u * CAP;

    int k = 0;
    for (; k + 8 <= n; k += 8) {
        uint4 iv = *(const uint4*)(row + k);
        int s0 = iv.x & 0xFFFF, s1 = iv.x >> 16;
        int s2 = iv.y & 0xFFFF, s3 = iv.y >> 16;
        int s4 = iv.z & 0xFFFF, s5 = iv.z >> 16;
        int s6 = iv.w & 0xFFFF, s7 = iv.w >> 16;
        f16x8 v0 = *(const f16x8*)(gp + (size_t)s0 * OUT_CH);
        f16x8 v1 = *(const f16x8*)(gp + (size_t)s1 * OUT_CH);
        f16x8 v2 = *(const f16x8*)(gp + (size_t)s2 * OUT_CH);
        f16x8 v3 = *(const f16x8*)(gp + (size_t)s3 * OUT_CH);
        f16x8 v4 = *(const f16x8*)(gp + (size_t)s4 * OUT_CH);
        f16x8 v5 = *(const f16x8*)(gp + (size_t)s5 * OUT_CH);
        f16x8 v6 = *(const f16x8*)(gp + (size_t)s6 * OUT_CH);
        f16x8 v7 = *(const f16x8*)(gp + (size_t)s7 * OUT_CH);
#pragma unroll
        for (int j = 0; j < 8; ++j)
            a[j] += (((float)v0[j] + (float)v1[j]) + ((float)v2[j] + (float)v3[j])) +
                    (((float)v4[j] + (float)v5[j]) + ((float)v6[j] + (float)v7[j]));
    }
    if (k + 4 <= n) {
        ushort4 s4v = *(const ushort4*)(row + k);
        f16x8 v0 = *(const f16x8*)(gp + (size_t)s4v.x * OUT_CH);
        f16x8 v1 = *(const f16x8*)(gp + (size_t)s4v.y * OUT_CH);
        f16x8 v2 = *(const f16x8*)(gp + (size_t)s4v.z * OUT_CH);
        f16x8 v3 = *(const f16x8*)(gp + (size_t)s4v.w * OUT_CH);
#pragma unroll
        for (int j = 0; j < 8; ++j)
            a[j] += ((float)v0[j] + (float)v1[j]) + ((float)v2[j] + (float)v3[j]);
        k += 4;
    }
    for (; k < n; ++k) {
        f16x8 v = *(const f16x8*)(gp + (size_t)row[k] * OUT_CH);
#pragma unroll
        for (int j = 0; j < 8; ++j) a[j] += (float)v[j];
    }

    float du = dis[u];
    float4* op = (float4*)(out + (size_t)u * OUT_CH + sub * 8);
    float4 o0, o1;
    o0.x = fmaxf(fmaf(du, a[0], b2[sub * 8 + 0]), 0.f);
    o0.y = fmaxf(fmaf(du, a[1], b2[sub * 8 + 1]), 0.f);
    o0.z = fmaxf(fmaf(du, a[2], b2[sub * 8 + 2]), 0.f);
    o0.w = fmaxf(fmaf(du, a[3], b2[sub * 8 + 3]), 0.f);
    o1.x = fmaxf(fmaf(du, a[4], b2[sub * 8 + 4]), 0.f);
    o1.y = fmaxf(fmaf(du, a[5], b2[sub * 8 + 5]), 0.f);
    o1.z = fmaxf(fmaf(du, a[6], b2[sub * 8 + 6]), 0.f);
    o1.w = fmaxf(fmaf(du, a[7], b2[sub * 8 + 7]), 0.f);
    op[0] = o0;
    op[1] = o1;
}

// ---------------- launch ----------------

extern "C" void kernel_launch(void* const* d_in, const int* in_sizes, int n_in,
                              void* d_out, int out_size, void* d_ws, size_t ws_size,
                              hipStream_t stream) {
    const float* x  = (const float*)d_in[0];
    const int* ei   = (const int*)d_in[1];
    const float* W1 = (const float*)d_in[2];
    const float* b1 = (const float*)d_in[3];
    const float* W2 = (const float*)d_in[4];
    const float* b2 = (const float*)d_in[5];
    float* out = (float*)d_out;

    const int* src = ei;
    const int* dst = ei + N_EDGES;

    char* ws = (char*)d_ws;
    size_t off = 0;
    auto alloc = [&](size_t bytes) -> void* {
        off = (off + 255) & ~(size_t)255;
        void* p = ws + off;
        off += bytes;
        return p;
    };
    int*   zbuf      = (int*)alloc((size_t)(NBINS * 2) * 4);    // binCnt | binCursor
    int*   binCnt    = zbuf;
    int*   binCursor = zbuf + NBINS;
    u32*   ebuf      = (u32*)alloc((size_t)N_EDGES * 4);        // 3.2 MB
    int*   cnt       = (int*)alloc((size_t)N_NODES * 4);
    float* dis       = (float*)alloc((size_t)N_NODES * 4);
    u16*   bucket    = (u16*)alloc((size_t)N_NODES * CAP * 2);  // 6.4 MB
    f16*   W1sw      = (f16*)alloc((size_t)IN_CH * HID_CH * 2);
    f16*   W2sw      = (f16*)alloc((size_t)HID_CH * OUT_CH * 2);
    f16*   g1        = (f16*)alloc((size_t)N_NODES * HID_CH * 2);  // prescaled, row-major
    f16*   g2        = (f16*)alloc((size_t)N_NODES * OUT_CH * 2);  // prescaled, row-major

    hipMemsetAsync(zbuf, 0, (size_t)(NBINS * 2) * 4, stream);

    // 1. fused histogram + weight swizzle
    k_pre<<<PBLOCKS + SWZ_BLOCKS, 256, 0, stream>>>(dst, binCnt, W1, W2, W1sw, W2sw);
    // 2. place   3. build (+cnt +dis)
    k_place<<<PBLOCKS, 256, 0, stream>>>(src, dst, binCnt, binCursor, ebuf, N_EDGES);
    k_build<<<NBINS, 256, 0, stream>>>(ebuf, binCnt, cnt, dis, bucket, N_NODES);

    // 4. layer-1 GEMM: g1 = dis*(x @ W1), row-major
    k_gemm1<<<(N_NODES + 63) / 64, 256, 0, stream>>>(x, W1sw, dis, g1, N_NODES);

    // 5. fused pull1 + layer-2 GEMM, 512-thread blocks (gather parallelism x2)
    k_pullgemm<<<(N_NODES + 63) / 64, 512, 0, stream>>>(g1, dis, b1, cnt, bucket,
                                                        W2sw, g2);

    // 6. pull2: out = relu(du*(g2[u]+sum g2[s]) + b2), fp32
    k_pull2<<<(N_NODES * 8 + 255) / 256, 256, 0, stream>>>(g2, dis, b2, cnt, bucket, out);
}

// Round 6
// 185.586 us; speedup vs baseline: 1.2121x; 1.0744x over previous
//
#include <hip/hip_runtime.h>

#define N_NODES 50000
#define N_EDGES 800000
#define IN_CH 256
#define HID_CH 128
#define OUT_CH 64
#define CAP 64       // bucket slots/node; deg~Poisson(16), P(deg>=64) ~ 1e-18
#define NBINS 196    // ceil(N/256): bin = dst >> 8
#define BINCAP 8192  // static per-bin ebuf region; bin load ~Poisson(4096), sigma 64
#define PCHUNK 3200
#define PBLOCKS 250  // 250*3200 == N_EDGES
#define SWZ_ELEMS (IN_CH * HID_CH + HID_CH * OUT_CH)  // 40960
#define SWZ_BLOCKS (SWZ_ELEMS / 256)                  // 160

typedef _Float16 f16;
typedef _Float16 f16x8 __attribute__((ext_vector_type(8)));
typedef float f32x4 __attribute__((ext_vector_type(4)));
typedef unsigned short u16;
typedef unsigned int u32;

// ---------------- W -> MFMA B-fragment swizzle ----------------
template <int K, int N>
__device__ __forceinline__ void swz(const float* __restrict__ W, f16* __restrict__ Bsw,
                                    int idx) {
    constexpr int NTILES = N / 16;
    int j = idx & 7;
    int lane = (idx >> 3) & 63;
    int rest = idx >> 9;
    int nt = rest % NTILES;
    int ks = rest / NTILES;
    int k = ks * 32 + (lane >> 4) * 8 + j;
    int n = nt * 16 + (lane & 15);
    Bsw[idx] = (f16)W[(size_t)k * N + n];
}

// ---------------- fused: place edges into STATIC bin regions + weight swizzle ----
// Static bases (bin b owns ebuf[b*BINCAP .. b*BINCAP+BINCAP)) kill the histogram
// dispatch and both 17-barrier scans. binCursor[b] accumulates the exact count.
__global__ __launch_bounds__(256) void k_place(const int* __restrict__ src,
                                               const int* __restrict__ dst,
                                               int* __restrict__ binCursor,
                                               u32* __restrict__ ebuf,
                                               const float* __restrict__ W1,
                                               const float* __restrict__ W2,
                                               f16* __restrict__ B1,
                                               f16* __restrict__ B2) {
    if ((int)blockIdx.x >= PBLOCKS) {
        int idx = ((int)blockIdx.x - PBLOCKS) * 256 + threadIdx.x;
        if (idx < IN_CH * HID_CH) {
            swz<IN_CH, HID_CH>(W1, B1, idx);
        } else {
            idx -= IN_CH * HID_CH;
            if (idx < HID_CH * OUT_CH) swz<HID_CH, OUT_CH>(W2, B2, idx);
        }
        return;
    }
    __shared__ u32 codes[PCHUNK];
    __shared__ int lcnt[NBINS], lbase[NBINS], lcur[NBINS];
    for (int i = threadIdx.x; i < NBINS; i += 256) lcnt[i] = 0;
    __syncthreads();
    int base = blockIdx.x * PCHUNK;
    for (int j = threadIdx.x; j < PCHUNK; j += 256) {
        u32 d = (u32)dst[base + j];
        codes[j] = (d << 16) | (u32)src[base + j];
        atomicAdd(&lcnt[d >> 8], 1);
    }
    __syncthreads();
    for (int i = threadIdx.x; i < NBINS; i += 256) {
        lbase[i] = i * BINCAP + atomicAdd(&binCursor[i], lcnt[i]);
        lcur[i] = 0;
    }
    __syncthreads();
    for (int j = threadIdx.x; j < PCHUNK; j += 256) {
        u32 c = codes[j];
        int b = c >> 24;
        int p = atomicAdd(&lcur[b], 1);
        int pos = lbase[b] + p;
        if (pos < (b + 1) * BINCAP) ebuf[pos] = c;   // overflow guard (never in practice)
    }
}

// ---------------- per-bin CSR build in LDS + cnt + dis (no scan: static bases) ----
__global__ __launch_bounds__(256) void k_build(const u32* __restrict__ ebuf,
                                               const int* __restrict__ binCursor,
                                               int* __restrict__ cnt,
                                               float* __restrict__ dis,
                                               u16* __restrict__ bucket, int N) {
    __shared__ int lcnt[256];
    __shared__ u16 lbuck[256 * CAP];   // 32 KB
    int t = threadIdx.x;
    lcnt[t] = 0;
    __syncthreads();
    int b = blockIdx.x;
    int count = binCursor[b];
    if (count > BINCAP) count = BINCAP;
    int s = b * BINCAP;
    int e = s + count;
    for (int i = s + t; i < e; i += 256) {
        u32 c = ebuf[i];
        int local = (c >> 16) & 255;
        int p = atomicAdd(&lcnt[local], 1);
        if (p < CAP) lbuck[local * CAP + p] = (u16)(c & 0xFFFFu);
    }
    __syncthreads();
    int nodeBase = b << 8;
    if (nodeBase + t < N) {
        cnt[nodeBase + t] = lcnt[t];
        dis[nodeBase + t] = rsqrtf((float)lcnt[t] + 1.0f);
    }
    // write only the 16B chunks that hold live entries
    const uint4* lsrc = (const uint4*)lbuck;
    uint4* gdst = (uint4*)(bucket + (size_t)nodeBase * CAP);
    for (int idx = t; idx < 256 * CAP / 8; idx += 256) {
        int row = idx >> 3;
        int chunk = idx & 7;
        if (nodeBase + row < N && (chunk << 3) < lcnt[row]) gdst[idx] = lsrc[idx];
    }
}

// ---------------- MFMA fp16 GEMM layer1: g1 = dis[m]*(x @ W1), row-major out ----
__global__ __launch_bounds__(256) void k_gemm1(const float* __restrict__ A,
                                               const f16* __restrict__ Bsw,
                                               const float* __restrict__ dis,
                                               f16* __restrict__ C, int M) {
    constexpr int K = IN_CH, N = HID_CH;
    constexpr int KSTEPS = K / 32, NTILES = N / 16;
    const int tid = threadIdx.x;
    const int wave = tid >> 6, lane = tid & 63;
    const int quad = lane >> 4, l16 = lane & 15;
    int row = blockIdx.x * 64 + wave * 16 + l16;
    const int rowc = row < M ? row : M - 1;

    f32x4 acc[NTILES];
#pragma unroll
    for (int t = 0; t < NTILES; ++t) acc[t] = (f32x4){0.f, 0.f, 0.f, 0.f};

#pragma unroll
    for (int ks = 0; ks < KSTEPS; ++ks) {
        f16x8 afrag;
        const float4* p = (const float4*)(A + (size_t)rowc * K + ks * 32 + quad * 8);
        float4 v0 = p[0], v1 = p[1];
        afrag[0] = (f16)v0.x; afrag[1] = (f16)v0.y;
        afrag[2] = (f16)v0.z; afrag[3] = (f16)v0.w;
        afrag[4] = (f16)v1.x; afrag[5] = (f16)v1.y;
        afrag[6] = (f16)v1.z; afrag[7] = (f16)v1.w;
#pragma unroll
        for (int t = 0; t < NTILES; ++t) {
            f16x8 bfrag = *(const f16x8*)(Bsw + (((size_t)ks * NTILES + t) * 64 + lane) * 8);
            acc[t] = __builtin_amdgcn_mfma_f32_16x16x32_f16(afrag, bfrag, acc[t], 0, 0, 0);
        }
    }

    int rbase = blockIdx.x * 64 + wave * 16 + quad * 4;
#pragma unroll
    for (int r = 0; r < 4; ++r) {
        int gr = rbase + r;
        if (gr < M) {
            float d = dis[gr];
#pragma unroll
            for (int t = 0; t < NTILES; ++t)
                C[(size_t)gr * N + t * 16 + l16] = (f16)(acc[t][r] * d);
        }
    }
}

// ---------------- fused pull1 + gemm2 (round-1 form, 256 threads) ----------------
// Phase A (gather): agg[u,c] = relu( du*(g1[u,c] + sum_s g1[s,c]) + b1[c] ) -> LDS
//   (g1 prescaled by dis[src], so plain sums; du folds the dst factor)
// Phase B (MFMA):   g2[u,:] = dis[u] * (agg[u,:] @ W2)
__global__ __launch_bounds__(256) void k_pullgemm(const f16* __restrict__ g1,
                                                  const float* __restrict__ dis,
                                                  const float* __restrict__ b1,
                                                  const int* __restrict__ cnt,
                                                  const u16* __restrict__ bucket,
                                                  const f16* __restrict__ B2sw,
                                                  f16* __restrict__ g2) {
    constexpr int LDSW = HID_CH + 8;       // 136 f16 = 272 B row stride
    __shared__ f16 aggl[64 * LDSW];        // 17.4 KB LDS
    const int tid = threadIdx.x;
    const int sub = tid & 15;              // channel octet 0..15
    const int nl = tid >> 4;               // node slot 0..15
    const int blockBase = (int)blockIdx.x * 64;

    const float4* b1p = (const float4*)(b1 + sub * 8);
    float4 bb0 = b1p[0], bb1 = b1p[1];
    float bv[8] = {bb0.x, bb0.y, bb0.z, bb0.w, bb1.x, bb1.y, bb1.z, bb1.w};

    // ---- phase A: gather 64 nodes (16 at a time) ----
    for (int it = 0; it < 4; ++it) {
        int lrow = it * 16 + nl;
        int u = blockBase + lrow;
        f16x8 o;
        if (u < N_NODES) {
            const f16* gp = g1 + sub * 8;
            f16x8 sv = *(const f16x8*)(gp + (size_t)u * HID_CH);
            float a[8];
#pragma unroll
            for (int j = 0; j < 8; ++j) a[j] = (float)sv[j];

            int n = cnt[u];
            if (n > CAP) n = CAP;
            const u16* row = bucket + u * CAP;

            int k = 0;
            for (; k + 8 <= n; k += 8) {
                uint4 iv = *(const uint4*)(row + k);
                int s0 = iv.x & 0xFFFF, s1 = iv.x >> 16;
                int s2 = iv.y & 0xFFFF, s3 = iv.y >> 16;
                int s4 = iv.z & 0xFFFF, s5 = iv.z >> 16;
                int s6 = iv.w & 0xFFFF, s7 = iv.w >> 16;
                f16x8 v0 = *(const f16x8*)(gp + (size_t)s0 * HID_CH);
                f16x8 v1 = *(const f16x8*)(gp + (size_t)s1 * HID_CH);
                f16x8 v2 = *(const f16x8*)(gp + (size_t)s2 * HID_CH);
                f16x8 v3 = *(const f16x8*)(gp + (size_t)s3 * HID_CH);
                f16x8 v4 = *(const f16x8*)(gp + (size_t)s4 * HID_CH);
                f16x8 v5 = *(const f16x8*)(gp + (size_t)s5 * HID_CH);
                f16x8 v6 = *(const f16x8*)(gp + (size_t)s6 * HID_CH);
                f16x8 v7 = *(const f16x8*)(gp + (size_t)s7 * HID_CH);
#pragma unroll
                for (int j = 0; j < 8; ++j)
                    a[j] += (((float)v0[j] + (float)v1[j]) + ((float)v2[j] + (float)v3[j])) +
                            (((float)v4[j] + (float)v5[j]) + ((float)v6[j] + (float)v7[j]));
            }
            if (k + 4 <= n) {
                ushort4 s4v = *(const ushort4*)(row + k);
                f16x8 v0 = *(const f16x8*)(gp + (size_t)s4v.x * HID_CH);
                f16x8 v1 = *(const f16x8*)(gp + (size_t)s4v.y * HID_CH);
                f16x8 v2 = *(const f16x8*)(gp + (size_t)s4v.z * HID_CH);
                f16x8 v3 = *(const f16x8*)(gp + (size_t)s4v.w * HID_CH);
#pragma unroll
                for (int j = 0; j < 8; ++j)
                    a[j] += ((float)v0[j] + (float)v1[j]) + ((float)v2[j] + (float)v3[j]);
                k += 4;
            }
            for (; k < n; ++k) {
                f16x8 v = *(const f16x8*)(gp + (size_t)row[k] * HID_CH);
#pragma unroll
                for (int j = 0; j < 8; ++j) a[j] += (float)v[j];
            }

            float du = dis[u];
#pragma unroll
            for (int j = 0; j < 8; ++j) {
                float t = fmaf(du, a[j], bv[j]);
                o[j] = (f16)(t > 0.f ? t : 0.f);   // relu(cvt) == cvt(relu) for f16
            }
        } else {
#pragma unroll
            for (int j = 0; j < 8; ++j) o[j] = (f16)0;
        }
        *(f16x8*)(aggl + (size_t)lrow * LDSW + sub * 8) = o;
    }
    __syncthreads();

    // ---- phase B: 64x64 MFMA tile, K=128, A from LDS ----
    constexpr int KSTEPS = HID_CH / 32, NTILES = OUT_CH / 16;
    const int wave = tid >> 6, lane = tid & 63;
    const int quad = lane >> 4, l16 = lane & 15;
    const int lrowA = wave * 16 + l16;

    f32x4 acc[NTILES];
#pragma unroll
    for (int t = 0; t < NTILES; ++t) acc[t] = (f32x4){0.f, 0.f, 0.f, 0.f};

#pragma unroll
    for (int ks = 0; ks < KSTEPS; ++ks) {
        f16x8 afrag = *(const f16x8*)(aggl + (size_t)lrowA * LDSW + ks * 32 + quad * 8);
#pragma unroll
        for (int t = 0; t < NTILES; ++t) {
            f16x8 bfrag = *(const f16x8*)(B2sw + (((size_t)ks * NTILES + t) * 64 + lane) * 8);
            acc[t] = __builtin_amdgcn_mfma_f32_16x16x32_f16(afrag, bfrag, acc[t], 0, 0, 0);
        }
    }

    int rbase = blockBase + wave * 16 + quad * 4;
#pragma unroll
    for (int r = 0; r < 4; ++r) {
        int gr = rbase + r;
        if (gr < N_NODES) {
            float d = dis[gr];
#pragma unroll
            for (int t = 0; t < NTILES; ++t)
                g2[(size_t)gr * OUT_CH + t * 16 + l16] = (f16)(acc[t][r] * d);
        }
    }
}

// ---------------- pull2: 8 lanes/node, f16x8 — 8 independent node-chains/wave ----------------
// out[u,c] = relu( du*(g2[u,c] + sum g2[s,c]) + b2[c] ), fp32.
__global__ __launch_bounds__(256) void k_pull2(const f16* __restrict__ g2,
                                               const float* __restrict__ dis,
                                               const float* __restrict__ b2,
                                               const int* __restrict__ cnt,
                                               const u16* __restrict__ bucket,
                                               float* __restrict__ out) {
    int gtid = blockIdx.x * 256 + threadIdx.x;
    int u = gtid >> 3;
    int sub = gtid & 7;
    if (u >= N_NODES) return;
    const f16* gp = g2 + sub * 8;

    f16x8 sv = *(const f16x8*)(gp + (size_t)u * OUT_CH);
    float a[8];
#pragma unroll
    for (int j = 0; j < 8; ++j) a[j] = (float)sv[j];

    int n = cnt[u];
    if (n > CAP) n = CAP;
    const u16* row = bucket + u * CAP;

    int k = 0;
    for (; k + 8 <= n; k += 8) {
        uint4 iv = *(const uint4*)(row + k);
        int s0 = iv.x & 0xFFFF, s1 = iv.x >> 16;
        int s2 = iv.y & 0xFFFF, s3 = iv.y >> 16;
        int s4 = iv.z & 0xFFFF, s5 = iv.z >> 16;
        int s6 = iv.w & 0xFFFF, s7 = iv.w >> 16;
        f16x8 v0 = *(const f16x8*)(gp + (size_t)s0 * OUT_CH);
        f16x8 v1 = *(const f16x8*)(gp + (size_t)s1 * OUT_CH);
        f16x8 v2 = *(const f16x8*)(gp + (size_t)s2 * OUT_CH);
        f16x8 v3 = *(const f16x8*)(gp + (size_t)s3 * OUT_CH);
        f16x8 v4 = *(const f16x8*)(gp + (size_t)s4 * OUT_CH);
        f16x8 v5 = *(const f16x8*)(gp + (size_t)s5 * OUT_CH);
        f16x8 v6 = *(const f16x8*)(gp + (size_t)s6 * OUT_CH);
        f16x8 v7 = *(const f16x8*)(gp + (size_t)s7 * OUT_CH);
#pragma unroll
        for (int j = 0; j < 8; ++j)
            a[j] += (((float)v0[j] + (float)v1[j]) + ((float)v2[j] + (float)v3[j])) +
                    (((float)v4[j] + (float)v5[j]) + ((float)v6[j] + (float)v7[j]));
    }
    if (k + 4 <= n) {
        ushort4 s4v = *(const ushort4*)(row + k);
        f16x8 v0 = *(const f16x8*)(gp + (size_t)s4v.x * OUT_CH);
        f16x8 v1 = *(const f16x8*)(gp + (size_t)s4v.y * OUT_CH);
        f16x8 v2 = *(const f16x8*)(gp + (size_t)s4v.z * OUT_CH);
        f16x8 v3 = *(const f16x8*)(gp + (size_t)s4v.w * OUT_CH);
#pragma unroll
        for (int j = 0; j < 8; ++j)
            a[j] += ((float)v0[j] + (float)v1[j]) + ((float)v2[j] + (float)v3[j]);
        k += 4;
    }
    for (; k < n; ++k) {
        f16x8 v = *(const f16x8*)(gp + (size_t)row[k] * OUT_CH);
#pragma unroll
        for (int j = 0; j < 8; ++j) a[j] += (float)v[j];
    }

    float du = dis[u];
    float4* op = (float4*)(out + (size_t)u * OUT_CH + sub * 8);
    float4 o0, o1;
    o0.x = fmaxf(fmaf(du, a[0], b2[sub * 8 + 0]), 0.f);
    o0.y = fmaxf(fmaf(du, a[1], b2[sub * 8 + 1]), 0.f);
    o0.z = fmaxf(fmaf(du, a[2], b2[sub * 8 + 2]), 0.f);
    o0.w = fmaxf(fmaf(du, a[3], b2[sub * 8 + 3]), 0.f);
    o1.x = fmaxf(fmaf(du, a[4], b2[sub * 8 + 4]), 0.f);
    o1.y = fmaxf(fmaf(du, a[5], b2[sub * 8 + 5]), 0.f);
    o1.z = fmaxf(fmaf(du, a[6], b2[sub * 8 + 6]), 0.f);
    o1.w = fmaxf(fmaf(du, a[7], b2[sub * 8 + 7]), 0.f);
    op[0] = o0;
    op[1] = o1;
}

// ---------------- launch ----------------

extern "C" void kernel_launch(void* const* d_in, const int* in_sizes, int n_in,
                              void* d_out, int out_size, void* d_ws, size_t ws_size,
                              hipStream_t stream) {
    const float* x  = (const float*)d_in[0];
    const int* ei   = (const int*)d_in[1];
    const float* W1 = (const float*)d_in[2];
    const float* b1 = (const float*)d_in[3];
    const float* W2 = (const float*)d_in[4];
    const float* b2 = (const float*)d_in[5];
    float* out = (float*)d_out;

    const int* src = ei;
    const int* dst = ei + N_EDGES;

    char* ws = (char*)d_ws;
    size_t off = 0;
    auto alloc = [&](size_t bytes) -> void* {
        off = (off + 255) & ~(size_t)255;
        void* p = ws + off;
        off += bytes;
        return p;
    };
    int*   binCursor = (int*)alloc((size_t)NBINS * 4);
    u32*   ebuf      = (u32*)alloc((size_t)NBINS * BINCAP * 4);   // 6.4 MB static regions
    int*   cnt       = (int*)alloc((size_t)N_NODES * 4);
    float* dis       = (float*)alloc((size_t)N_NODES * 4);
    u16*   bucket    = (u16*)alloc((size_t)N_NODES * CAP * 2);    // 6.4 MB
    f16*   W1sw      = (f16*)alloc((size_t)IN_CH * HID_CH * 2);
    f16*   W2sw      = (f16*)alloc((size_t)HID_CH * OUT_CH * 2);
    f16*   g1        = (f16*)alloc((size_t)N_NODES * HID_CH * 2); // prescaled, row-major
    f16*   g2        = (f16*)alloc((size_t)N_NODES * OUT_CH * 2); // prescaled, row-major

    hipMemsetAsync(binCursor, 0, (size_t)NBINS * 4, stream);

    // 1. fused static-base edge placement + weight swizzle (no histogram needed)
    k_place<<<PBLOCKS + SWZ_BLOCKS, 256, 0, stream>>>(src, dst, binCursor, ebuf,
                                                      W1, W2, W1sw, W2sw);
    // 2. build (+cnt +dis), no scan
    k_build<<<NBINS, 256, 0, stream>>>(ebuf, binCursor, cnt, dis, bucket, N_NODES);

    // 3. layer-1 GEMM: g1 = dis*(x @ W1), row-major
    k_gemm1<<<(N_NODES + 63) / 64, 256, 0, stream>>>(x, W1sw, dis, g1, N_NODES);

    // 4. fused pull1 + layer-2 GEMM
    k_pullgemm<<<(N_NODES + 63) / 64, 256, 0, stream>>>(g1, dis, b1, cnt, bucket,
                                                        W2sw, g2);

    // 5. pull2: out = relu(du*(g2[u]+sum g2[s]) + b2), fp32
    k_pull2<<<(N_NODES * 8 + 255) / 256, 256, 0, stream>>>(g2, dis, b2, cnt, bucket, out);
}